// Round 3
// baseline (1204.307 us; speedup 1.0000x reference)
//
#include <hip/hip_runtime.h>
#include <hip/hip_bf16.h>
#include <cstdint>

#define NN 50000
#define NE 600000
#define DD 128
#define ROWS 32

// ---------------------------------------------------------------------------
// Kernel 1: edge scatter-add (mean aggregation numerator + counts)
// 32 lanes per edge; float4 gather from x[src], 4 fp32 atomics into agg[dst].
// ---------------------------------------------------------------------------
__global__ __launch_bounds__(256) void scatter_kernel(
    const float* __restrict__ x, const int* __restrict__ ei,
    float* __restrict__ agg, float* __restrict__ counts)
{
    int t = blockIdx.x * 256 + threadIdx.x;
    int e = t >> 5;
    if (e >= NE) return;
    int lane = t & 31;
    int src = ei[e];
    int dst = ei[NE + e];
    const float4 v = *reinterpret_cast<const float4*>(x + (size_t)src * DD + lane * 4);
    float* base = agg + (size_t)dst * DD + lane * 4;
    unsafeAtomicAdd(base + 0, v.x);
    unsafeAtomicAdd(base + 1, v.y);
    unsafeAtomicAdd(base + 2, v.z);
    unsafeAtomicAdd(base + 3, v.w);
    if (lane == 0) unsafeAtomicAdd(counts + dst, 1.0f);
}

// ---------------------------------------------------------------------------
// Kernel 2: out = ELU( (agg/cnt) @ W_l^T + b_l + x @ W_r^T ), f32 store.
// Block: 256 threads, 32 rows. LDS tile As[r][0..127]=agg/cnt, [128..255]=x.
// Thread (rg,cg): rows {rg+8i}, cols {cg*4+j}; 4x4 register tile, K in f32.
// Row stride 260 floats: staging writes conflict-free (consec k), compute
// reads conflict-free (260*rg mod 32 = 4*rg spreads 8 rgs over all banks).
// ---------------------------------------------------------------------------
__global__ __launch_bounds__(256) void finish_kernel(
    const float* __restrict__ agg, const float* __restrict__ counts,
    const float* __restrict__ x,
    const float* __restrict__ W_l, const float* __restrict__ b_l,
    const float* __restrict__ W_r,
    float* __restrict__ out)
{
    __shared__ float As[ROWS][260];
    const int row0 = blockIdx.x * ROWS;
    const int t = threadIdx.x;

    // stage: coalesced global reads, conflict-free LDS writes
    for (int i = t; i < ROWS * DD; i += 256) {
        int r = i >> 7;
        int k = i & 127;
        int row = row0 + r;
        float a = 0.f, xv = 0.f;
        if (row < NN) {
            float c = counts[row];
            float s = 1.0f / fmaxf(c, 1.0f);
            a  = agg[(size_t)row * DD + k] * s;
            xv = x[(size_t)row * DD + k];
        }
        As[r][k]      = a;
        As[r][DD + k] = xv;
    }
    __syncthreads();

    const int rg = t & 7;    // 8 row groups (strided rows rg+8i)
    const int cg = t >> 3;   // 32 col groups (wave covers 8 consecutive cgs)
    const int c0 = cg * 4;

    float acc[4][4];
    #pragma unroll
    for (int i = 0; i < 4; i++)
        #pragma unroll
        for (int j = 0; j < 4; j++) acc[i][j] = 0.f;

    // phase 1: (agg/cnt) @ W_l^T
    for (int k = 0; k < DD; k += 4) {
        float4 av[4], wv[4];
        #pragma unroll
        for (int i = 0; i < 4; i++)
            av[i] = *reinterpret_cast<const float4*>(&As[rg + 8 * i][k]);
        #pragma unroll
        for (int j = 0; j < 4; j++)
            wv[j] = *reinterpret_cast<const float4*>(W_l + (size_t)(c0 + j) * DD + k);
        #pragma unroll
        for (int i = 0; i < 4; i++)
            #pragma unroll
            for (int j = 0; j < 4; j++)
                acc[i][j] += av[i].x * wv[j].x + av[i].y * wv[j].y +
                             av[i].z * wv[j].z + av[i].w * wv[j].w;
    }
    // phase 2: x @ W_r^T
    for (int k = 0; k < DD; k += 4) {
        float4 av[4], wv[4];
        #pragma unroll
        for (int i = 0; i < 4; i++)
            av[i] = *reinterpret_cast<const float4*>(&As[rg + 8 * i][DD + k]);
        #pragma unroll
        for (int j = 0; j < 4; j++)
            wv[j] = *reinterpret_cast<const float4*>(W_r + (size_t)(c0 + j) * DD + k);
        #pragma unroll
        for (int i = 0; i < 4; i++)
            #pragma unroll
            for (int j = 0; j < 4; j++)
                acc[i][j] += av[i].x * wv[j].x + av[i].y * wv[j].y +
                             av[i].z * wv[j].z + av[i].w * wv[j].w;
    }

    // epilogue: + b_l, ELU, f32 float4 store
    const float4 bv = *reinterpret_cast<const float4*>(b_l + c0);
    #pragma unroll
    for (int i = 0; i < 4; i++) {
        int row = row0 + rg + 8 * i;
        if (row < NN) {
            float4 o;
            o.x = acc[i][0] + bv.x;
            o.y = acc[i][1] + bv.y;
            o.z = acc[i][2] + bv.z;
            o.w = acc[i][3] + bv.w;
            o.x = o.x > 0.f ? o.x : expm1f(o.x);
            o.y = o.y > 0.f ? o.y : expm1f(o.y);
            o.z = o.z > 0.f ? o.z : expm1f(o.z);
            o.w = o.w > 0.f ? o.w : expm1f(o.w);
            *reinterpret_cast<float4*>(out + (size_t)row * DD + c0) = o;
        }
    }
}

// ---------------------------------------------------------------------------
// Kernel 3: edge_index passthrough as f32 (output 1 of the tuple)
// ---------------------------------------------------------------------------
__global__ __launch_bounds__(256) void eidx_kernel(
    const int* __restrict__ ei, float* __restrict__ oe)
{
    int i = blockIdx.x * 256 + threadIdx.x;
    if (i < 2 * NE) oe[i] = (float)ei[i];
}

extern "C" void kernel_launch(void* const* d_in, const int* in_sizes, int n_in,
                              void* d_out, int out_size, void* d_ws, size_t ws_size,
                              hipStream_t stream)
{
    const float* x   = (const float*)d_in[0];
    const int*   ei  = (const int*)d_in[1];
    const float* W_l = (const float*)d_in[2];
    const float* b_l = (const float*)d_in[3];
    const float* W_r = (const float*)d_in[4];
    float* out = (float*)d_out;

    float* agg    = (float*)d_ws;
    float* counts = agg + (size_t)NN * DD;

    // ws is re-poisoned to 0xAA before every launch: must re-zero every call
    (void)hipMemsetAsync(d_ws, 0, ((size_t)NN * DD + NN) * sizeof(float), stream);

    int sb = (NE * 32 + 255) / 256;
    scatter_kernel<<<sb, 256, 0, stream>>>(x, ei, agg, counts);

    int fb = (NN + ROWS - 1) / ROWS;
    finish_kernel<<<fb, 256, 0, stream>>>(agg, counts, x, W_l, b_l, W_r, out);

    int eb = (2 * NE + 255) / 256;
    eidx_kernel<<<eb, 256, 0, stream>>>(ei, out + (size_t)NN * DD);
}

// Round 4
// 380.149 us; speedup vs baseline: 3.1680x; 3.1680x over previous
//
#include <hip/hip_runtime.h>
#include <hip/hip_bf16.h>
#include <cstdint>

#define NN 50000
#define NE 600000
#define DD 128
#define ROWS 32

// ws layout: counts[NN] | offsets[NN] | cursor[NN] | srcs_sorted[NE]  (~3 MB)

// ---------------------------------------------------------------------------
// Kernel 1: histogram of dst degrees (int atomics into 200 KB, L2-resident)
// ---------------------------------------------------------------------------
__global__ __launch_bounds__(256) void hist_kernel(
    const int* __restrict__ ei, int* __restrict__ counts)
{
    int e = blockIdx.x * 256 + threadIdx.x;
    if (e < NE) atomicAdd(&counts[ei[NE + e]], 1);
}

// ---------------------------------------------------------------------------
// Kernel 2: exclusive scan of counts -> offsets, cursor (single 1024-thr block)
// ---------------------------------------------------------------------------
__global__ __launch_bounds__(1024) void scan_kernel(
    const int* __restrict__ counts, int* __restrict__ offsets,
    int* __restrict__ cursor)
{
    __shared__ int sums[1024];
    const int t = threadIdx.x;
    const int CH = (NN + 1023) / 1024;   // 49
    const int base = t * CH;
    int s = 0;
    for (int i = 0; i < CH; i++) {
        int idx = base + i;
        if (idx < NN) s += counts[idx];
    }
    sums[t] = s;
    __syncthreads();
    // Hillis-Steele inclusive scan (read-all / barrier / write-all / barrier)
    for (int off = 1; off < 1024; off <<= 1) {
        int v = sums[t];
        int u = (t >= off) ? sums[t - off] : 0;
        __syncthreads();
        sums[t] = v + u;
        __syncthreads();
    }
    int run = (t == 0) ? 0 : sums[t - 1];
    for (int i = 0; i < CH; i++) {
        int idx = base + i;
        if (idx < NN) {
            offsets[idx] = run;
            cursor[idx]  = run;
            run += counts[idx];
        }
    }
}

// ---------------------------------------------------------------------------
// Kernel 3: counting-sort edges by dst: srcs_sorted[segment(dst)] = src
// ---------------------------------------------------------------------------
__global__ __launch_bounds__(256) void reorder_kernel(
    const int* __restrict__ ei, int* __restrict__ cursor,
    int* __restrict__ srcs)
{
    int e = blockIdx.x * 256 + threadIdx.x;
    if (e < NE) {
        int src = ei[e];
        int dst = ei[NE + e];
        int p = atomicAdd(&cursor[dst], 1);
        srcs[p] = src;
    }
}

// ---------------------------------------------------------------------------
// Kernel 4 (fused): gather-mean into LDS, then
// out = ELU( agg @ W_l^T + b_l + x @ W_r^T ), f32 store.
// Block: 256 threads / 4 waves, 32 rows. Wave wv gathers nodes wv*8..wv*8+7:
// whole wave reads one neighbor row per step (float2/lane = 512B coalesced),
// 4 independent accumulators for MLP. Edge-list addrs are wave-uniform ->
// scalar loads. Then the proven 4x4-register-tile dual GEMM (stride-260 LDS).
// ---------------------------------------------------------------------------
__global__ __launch_bounds__(256) void finish_kernel(
    const int* __restrict__ offsets, const int* __restrict__ counts,
    const int* __restrict__ srcs, const float* __restrict__ x,
    const float* __restrict__ W_l, const float* __restrict__ b_l,
    const float* __restrict__ W_r, float* __restrict__ out)
{
    __shared__ float As[ROWS][260];
    const int row0 = blockIdx.x * ROWS;
    const int t = threadIdx.x;

    // stage x rows (cols 128..255 of the tile), coalesced
    for (int i = t; i < ROWS * DD; i += 256) {
        int r = i >> 7, k = i & 127;
        int row = row0 + r;
        As[r][DD + k] = (row < NN) ? x[(size_t)row * DD + k] : 0.f;
    }

    // gather-mean agg rows (cols 0..127)
    const int wv = t >> 6;   // wave id 0..3
    const int ln = t & 63;   // lane
    for (int rr = 0; rr < 8; rr++) {
        int r = wv * 8 + rr;
        int node = row0 + r;
        float a0x = 0.f, a0y = 0.f, a1x = 0.f, a1y = 0.f;
        float a2x = 0.f, a2y = 0.f, a3x = 0.f, a3y = 0.f;
        float scale = 0.f;
        if (node < NN) {   // wave-uniform branch
            int beg = __builtin_amdgcn_readfirstlane(offsets[node]);
            int cnt = __builtin_amdgcn_readfirstlane(counts[node]);
            int e = beg, end = beg + cnt;
            for (; e + 4 <= end; e += 4) {
                int s0 = srcs[e], s1 = srcs[e + 1];
                int s2 = srcs[e + 2], s3 = srcs[e + 3];
                float2 v0 = *reinterpret_cast<const float2*>(x + (size_t)s0 * DD + 2 * ln);
                float2 v1 = *reinterpret_cast<const float2*>(x + (size_t)s1 * DD + 2 * ln);
                float2 v2 = *reinterpret_cast<const float2*>(x + (size_t)s2 * DD + 2 * ln);
                float2 v3 = *reinterpret_cast<const float2*>(x + (size_t)s3 * DD + 2 * ln);
                a0x += v0.x; a0y += v0.y;
                a1x += v1.x; a1y += v1.y;
                a2x += v2.x; a2y += v2.y;
                a3x += v3.x; a3y += v3.y;
            }
            for (; e < end; e++) {
                int s0 = srcs[e];
                float2 v0 = *reinterpret_cast<const float2*>(x + (size_t)s0 * DD + 2 * ln);
                a0x += v0.x; a0y += v0.y;
            }
            scale = 1.0f / fmaxf((float)cnt, 1.0f);
        }
        float2 st;
        st.x = (a0x + a1x + a2x + a3x) * scale;
        st.y = (a0y + a1y + a2y + a3y) * scale;
        *reinterpret_cast<float2*>(&As[r][2 * ln]) = st;
    }
    __syncthreads();

    const int rg = t & 7;    // 8 row groups (rows rg+8i)
    const int cg = t >> 3;   // 32 col groups
    const int c0 = cg * 4;

    float acc[4][4];
    #pragma unroll
    for (int i = 0; i < 4; i++)
        #pragma unroll
        for (int j = 0; j < 4; j++) acc[i][j] = 0.f;

    // phase 1: agg @ W_l^T
    for (int k = 0; k < DD; k += 4) {
        float4 av[4], wvv[4];
        #pragma unroll
        for (int i = 0; i < 4; i++)
            av[i] = *reinterpret_cast<const float4*>(&As[rg + 8 * i][k]);
        #pragma unroll
        for (int j = 0; j < 4; j++)
            wvv[j] = *reinterpret_cast<const float4*>(W_l + (size_t)(c0 + j) * DD + k);
        #pragma unroll
        for (int i = 0; i < 4; i++)
            #pragma unroll
            for (int j = 0; j < 4; j++)
                acc[i][j] += av[i].x * wvv[j].x + av[i].y * wvv[j].y +
                             av[i].z * wvv[j].z + av[i].w * wvv[j].w;
    }
    // phase 2: x @ W_r^T
    for (int k = 0; k < DD; k += 4) {
        float4 av[4], wvv[4];
        #pragma unroll
        for (int i = 0; i < 4; i++)
            av[i] = *reinterpret_cast<const float4*>(&As[rg + 8 * i][DD + k]);
        #pragma unroll
        for (int j = 0; j < 4; j++)
            wvv[j] = *reinterpret_cast<const float4*>(W_r + (size_t)(c0 + j) * DD + k);
        #pragma unroll
        for (int i = 0; i < 4; i++)
            #pragma unroll
            for (int j = 0; j < 4; j++)
                acc[i][j] += av[i].x * wvv[j].x + av[i].y * wvv[j].y +
                             av[i].z * wvv[j].z + av[i].w * wvv[j].w;
    }

    // epilogue: + b_l, ELU, f32 float4 store
    const float4 bv = *reinterpret_cast<const float4*>(b_l + c0);
    #pragma unroll
    for (int i = 0; i < 4; i++) {
        int row = row0 + rg + 8 * i;
        if (row < NN) {
            float4 o;
            o.x = acc[i][0] + bv.x;
            o.y = acc[i][1] + bv.y;
            o.z = acc[i][2] + bv.z;
            o.w = acc[i][3] + bv.w;
            o.x = o.x > 0.f ? o.x : expm1f(o.x);
            o.y = o.y > 0.f ? o.y : expm1f(o.y);
            o.z = o.z > 0.f ? o.z : expm1f(o.z);
            o.w = o.w > 0.f ? o.w : expm1f(o.w);
            *reinterpret_cast<float4*>(out + (size_t)row * DD + c0) = o;
        }
    }
}

// ---------------------------------------------------------------------------
// Kernel 5: edge_index passthrough as f32 (output 1 of the tuple)
// ---------------------------------------------------------------------------
__global__ __launch_bounds__(256) void eidx_kernel(
    const int* __restrict__ ei, float* __restrict__ oe)
{
    int i = blockIdx.x * 256 + threadIdx.x;
    if (i < 2 * NE) oe[i] = (float)ei[i];
}

extern "C" void kernel_launch(void* const* d_in, const int* in_sizes, int n_in,
                              void* d_out, int out_size, void* d_ws, size_t ws_size,
                              hipStream_t stream)
{
    const float* x   = (const float*)d_in[0];
    const int*   ei  = (const int*)d_in[1];
    const float* W_l = (const float*)d_in[2];
    const float* b_l = (const float*)d_in[3];
    const float* W_r = (const float*)d_in[4];
    float* out = (float*)d_out;

    int* counts  = (int*)d_ws;
    int* offsets = counts + NN;
    int* cursor  = offsets + NN;
    int* srcs    = cursor + NN;

    // counts must be zero each launch (ws re-poisoned to 0xAA)
    (void)hipMemsetAsync(counts, 0, (size_t)NN * sizeof(int), stream);

    int eb = (NE + 255) / 256;
    hist_kernel<<<eb, 256, 0, stream>>>(ei, counts);
    scan_kernel<<<1, 1024, 0, stream>>>(counts, offsets, cursor);
    reorder_kernel<<<eb, 256, 0, stream>>>(ei, cursor, srcs);

    int fb = (NN + ROWS - 1) / ROWS;
    finish_kernel<<<fb, 256, 0, stream>>>(offsets, counts, srcs, x,
                                          W_l, b_l, W_r, out);

    int ib = (2 * NE + 255) / 256;
    eidx_kernel<<<ib, 256, 0, stream>>>(ei, out + (size_t)NN * DD);
}

// Round 5
// 265.286 us; speedup vs baseline: 4.5397x; 1.4330x over previous
//
#include <hip/hip_runtime.h>
#include <hip/hip_bf16.h>
#include <cstdint>

#define NN 50000
#define NE 600000
#define DD 128
#define ROWS 32
#define SCAN_BLKS 49   // ceil(50000/1024)

// ws layout: counts[NN] | offsets[NN] | cursor[NN] | srcs[NE] | blocksums[64] | blockoffs[64]

// ---------------------------------------------------------------------------
// Kernel 1: histogram of dst degrees (int atomics into 200 KB, L2-resident)
// ---------------------------------------------------------------------------
__global__ __launch_bounds__(256) void hist_kernel(
    const int* __restrict__ ei, int* __restrict__ counts)
{
    int e = blockIdx.x * 256 + threadIdx.x;
    if (e < NE) atomicAdd(&counts[ei[NE + e]], 1);
}

// ---------------------------------------------------------------------------
// Scan stage 1: per-block sums (49 blocks x 256 thr x int4 = 1024 counts/blk)
// ---------------------------------------------------------------------------
__global__ __launch_bounds__(256) void scan1_kernel(
    const int* __restrict__ counts, int* __restrict__ blocksums)
{
    const int t = threadIdx.x;
    const int base = blockIdx.x * 1024 + t * 4;
    int4 v;
    if (base + 3 < NN) {
        v = *reinterpret_cast<const int4*>(counts + base);
    } else {
        v.x = (base + 0 < NN) ? counts[base + 0] : 0;
        v.y = (base + 1 < NN) ? counts[base + 1] : 0;
        v.z = (base + 2 < NN) ? counts[base + 2] : 0;
        v.w = (base + 3 < NN) ? counts[base + 3] : 0;
    }
    int s = v.x + v.y + v.z + v.w;
    #pragma unroll
    for (int m = 1; m < 64; m <<= 1) s += __shfl_xor(s, m, 64);
    __shared__ int ws[4];
    const int wv = t >> 6, ln = t & 63;
    if (ln == 0) ws[wv] = s;
    __syncthreads();
    if (t == 0) blocksums[blockIdx.x] = ws[0] + ws[1] + ws[2] + ws[3];
}

// ---------------------------------------------------------------------------
// Scan stage 2: one wave scans the 49 block sums -> exclusive block offsets
// ---------------------------------------------------------------------------
__global__ __launch_bounds__(64) void scan2_kernel(
    const int* __restrict__ blocksums, int* __restrict__ blockoffs)
{
    const int ln = threadIdx.x;
    int v = (ln < SCAN_BLKS) ? blocksums[ln] : 0;
    int s = v;
    #pragma unroll
    for (int d = 1; d < 64; d <<= 1) {
        int n = __shfl_up(s, d, 64);
        if (ln >= d) s += n;
    }
    if (ln < SCAN_BLKS) blockoffs[ln] = s - v;   // exclusive
}

// ---------------------------------------------------------------------------
// Scan stage 3: full exclusive scan -> offsets & cursor (int4 stores)
// ---------------------------------------------------------------------------
__global__ __launch_bounds__(256) void scan3_kernel(
    const int* __restrict__ counts, const int* __restrict__ blockoffs,
    int* __restrict__ offsets, int* __restrict__ cursor)
{
    const int t = threadIdx.x;
    const int base = blockIdx.x * 1024 + t * 4;
    int4 v;
    if (base + 3 < NN) {
        v = *reinterpret_cast<const int4*>(counts + base);
    } else {
        v.x = (base + 0 < NN) ? counts[base + 0] : 0;
        v.y = (base + 1 < NN) ? counts[base + 1] : 0;
        v.z = (base + 2 < NN) ? counts[base + 2] : 0;
        v.w = (base + 3 < NN) ? counts[base + 3] : 0;
    }
    const int sum = v.x + v.y + v.z + v.w;
    int s = sum;
    const int wv = t >> 6, ln = t & 63;
    #pragma unroll
    for (int d = 1; d < 64; d <<= 1) {   // inclusive wave scan
        int n = __shfl_up(s, d, 64);
        if (ln >= d) s += n;
    }
    __shared__ int ws[4];
    if (ln == 63) ws[wv] = s;
    __syncthreads();
    int woff = 0;
    #pragma unroll
    for (int i = 0; i < 4; i++) if (i < wv) woff += ws[i];
    const int excl = s - sum + woff + blockoffs[blockIdx.x];
    int4 o;
    o.x = excl;
    o.y = o.x + v.x;
    o.z = o.y + v.y;
    o.w = o.z + v.z;
    if (base + 3 < NN) {
        *reinterpret_cast<int4*>(offsets + base) = o;
        *reinterpret_cast<int4*>(cursor + base) = o;
    } else {
        if (base + 0 < NN) { offsets[base + 0] = o.x; cursor[base + 0] = o.x; }
        if (base + 1 < NN) { offsets[base + 1] = o.y; cursor[base + 1] = o.y; }
        if (base + 2 < NN) { offsets[base + 2] = o.z; cursor[base + 2] = o.z; }
        if (base + 3 < NN) { offsets[base + 3] = o.w; cursor[base + 3] = o.w; }
    }
}

// ---------------------------------------------------------------------------
// Kernel 3: counting-sort edges by dst: srcs_sorted[segment(dst)] = src
// ---------------------------------------------------------------------------
__global__ __launch_bounds__(256) void reorder_kernel(
    const int* __restrict__ ei, int* __restrict__ cursor,
    int* __restrict__ srcs)
{
    int e = blockIdx.x * 256 + threadIdx.x;
    if (e < NE) {
        int src = ei[e];
        int dst = ei[NE + e];
        int p = atomicAdd(&cursor[dst], 1);
        srcs[p] = src;
    }
}

// ---------------------------------------------------------------------------
// Kernel 4 (fused): gather-mean into LDS, then
// out = ELU( agg @ W_l^T + b_l + x @ W_r^T ), f32 store.
// ---------------------------------------------------------------------------
__global__ __launch_bounds__(256) void finish_kernel(
    const int* __restrict__ offsets, const int* __restrict__ counts,
    const int* __restrict__ srcs, const float* __restrict__ x,
    const float* __restrict__ W_l, const float* __restrict__ b_l,
    const float* __restrict__ W_r, float* __restrict__ out)
{
    __shared__ float As[ROWS][260];
    const int row0 = blockIdx.x * ROWS;
    const int t = threadIdx.x;

    // stage x rows (cols 128..255 of the tile), coalesced
    for (int i = t; i < ROWS * DD; i += 256) {
        int r = i >> 7, k = i & 127;
        int row = row0 + r;
        As[r][DD + k] = (row < NN) ? x[(size_t)row * DD + k] : 0.f;
    }

    // gather-mean agg rows (cols 0..127); one wave per 8 nodes
    const int wv = t >> 6;
    const int ln = t & 63;
    for (int rr = 0; rr < 8; rr++) {
        int r = wv * 8 + rr;
        int node = row0 + r;
        float a0x = 0.f, a0y = 0.f, a1x = 0.f, a1y = 0.f;
        float a2x = 0.f, a2y = 0.f, a3x = 0.f, a3y = 0.f;
        float scale = 0.f;
        if (node < NN) {   // wave-uniform branch
            int beg = __builtin_amdgcn_readfirstlane(offsets[node]);
            int cnt = __builtin_amdgcn_readfirstlane(counts[node]);
            int e = beg, end = beg + cnt;
            for (; e + 4 <= end; e += 4) {
                int s0 = srcs[e], s1 = srcs[e + 1];
                int s2 = srcs[e + 2], s3 = srcs[e + 3];
                float2 v0 = *reinterpret_cast<const float2*>(x + (size_t)s0 * DD + 2 * ln);
                float2 v1 = *reinterpret_cast<const float2*>(x + (size_t)s1 * DD + 2 * ln);
                float2 v2 = *reinterpret_cast<const float2*>(x + (size_t)s2 * DD + 2 * ln);
                float2 v3 = *reinterpret_cast<const float2*>(x + (size_t)s3 * DD + 2 * ln);
                a0x += v0.x; a0y += v0.y;
                a1x += v1.x; a1y += v1.y;
                a2x += v2.x; a2y += v2.y;
                a3x += v3.x; a3y += v3.y;
            }
            for (; e < end; e++) {
                int s0 = srcs[e];
                float2 v0 = *reinterpret_cast<const float2*>(x + (size_t)s0 * DD + 2 * ln);
                a0x += v0.x; a0y += v0.y;
            }
            scale = 1.0f / fmaxf((float)cnt, 1.0f);
        }
        float2 st;
        st.x = (a0x + a1x + a2x + a3x) * scale;
        st.y = (a0y + a1y + a2y + a3y) * scale;
        *reinterpret_cast<float2*>(&As[r][2 * ln]) = st;
    }
    __syncthreads();

    const int rg = t & 7;
    const int cg = t >> 3;
    const int c0 = cg * 4;

    float acc[4][4];
    #pragma unroll
    for (int i = 0; i < 4; i++)
        #pragma unroll
        for (int j = 0; j < 4; j++) acc[i][j] = 0.f;

    // phase 1: agg @ W_l^T
    for (int k = 0; k < DD; k += 4) {
        float4 av[4], wvv[4];
        #pragma unroll
        for (int i = 0; i < 4; i++)
            av[i] = *reinterpret_cast<const float4*>(&As[rg + 8 * i][k]);
        #pragma unroll
        for (int j = 0; j < 4; j++)
            wvv[j] = *reinterpret_cast<const float4*>(W_l + (size_t)(c0 + j) * DD + k);
        #pragma unroll
        for (int i = 0; i < 4; i++)
            #pragma unroll
            for (int j = 0; j < 4; j++)
                acc[i][j] += av[i].x * wvv[j].x + av[i].y * wvv[j].y +
                             av[i].z * wvv[j].z + av[i].w * wvv[j].w;
    }
    // phase 2: x @ W_r^T
    for (int k = 0; k < DD; k += 4) {
        float4 av[4], wvv[4];
        #pragma unroll
        for (int i = 0; i < 4; i++)
            av[i] = *reinterpret_cast<const float4*>(&As[rg + 8 * i][DD + k]);
        #pragma unroll
        for (int j = 0; j < 4; j++)
            wvv[j] = *reinterpret_cast<const float4*>(W_r + (size_t)(c0 + j) * DD + k);
        #pragma unroll
        for (int i = 0; i < 4; i++)
            #pragma unroll
            for (int j = 0; j < 4; j++)
                acc[i][j] += av[i].x * wvv[j].x + av[i].y * wvv[j].y +
                             av[i].z * wvv[j].z + av[i].w * wvv[j].w;
    }

    // epilogue: + b_l, ELU, f32 float4 store
    const float4 bv = *reinterpret_cast<const float4*>(b_l + c0);
    #pragma unroll
    for (int i = 0; i < 4; i++) {
        int row = row0 + rg + 8 * i;
        if (row < NN) {
            float4 o;
            o.x = acc[i][0] + bv.x;
            o.y = acc[i][1] + bv.y;
            o.z = acc[i][2] + bv.z;
            o.w = acc[i][3] + bv.w;
            o.x = o.x > 0.f ? o.x : expm1f(o.x);
            o.y = o.y > 0.f ? o.y : expm1f(o.y);
            o.z = o.z > 0.f ? o.z : expm1f(o.z);
            o.w = o.w > 0.f ? o.w : expm1f(o.w);
            *reinterpret_cast<float4*>(out + (size_t)row * DD + c0) = o;
        }
    }
}

// ---------------------------------------------------------------------------
// Kernel 5: edge_index passthrough as f32 (output 1 of the tuple)
// ---------------------------------------------------------------------------
__global__ __launch_bounds__(256) void eidx_kernel(
    const int* __restrict__ ei, float* __restrict__ oe)
{
    int i = blockIdx.x * 256 + threadIdx.x;
    if (i < 2 * NE) oe[i] = (float)ei[i];
}

extern "C" void kernel_launch(void* const* d_in, const int* in_sizes, int n_in,
                              void* d_out, int out_size, void* d_ws, size_t ws_size,
                              hipStream_t stream)
{
    const float* x   = (const float*)d_in[0];
    const int*   ei  = (const int*)d_in[1];
    const float* W_l = (const float*)d_in[2];
    const float* b_l = (const float*)d_in[3];
    const float* W_r = (const float*)d_in[4];
    float* out = (float*)d_out;

    int* counts    = (int*)d_ws;
    int* offsets   = counts + NN;
    int* cursor    = offsets + NN;
    int* srcs      = cursor + NN;
    int* blocksums = srcs + NE;
    int* blockoffs = blocksums + 64;

    // counts must be zero each launch (ws re-poisoned to 0xAA)
    (void)hipMemsetAsync(counts, 0, (size_t)NN * sizeof(int), stream);

    int eb = (NE + 255) / 256;
    hist_kernel<<<eb, 256, 0, stream>>>(ei, counts);
    scan1_kernel<<<SCAN_BLKS, 256, 0, stream>>>(counts, blocksums);
    scan2_kernel<<<1, 64, 0, stream>>>(blocksums, blockoffs);
    scan3_kernel<<<SCAN_BLKS, 256, 0, stream>>>(counts, blockoffs, offsets, cursor);
    reorder_kernel<<<eb, 256, 0, stream>>>(ei, cursor, srcs);

    int fb = (NN + ROWS - 1) / ROWS;
    finish_kernel<<<fb, 256, 0, stream>>>(offsets, counts, srcs, x,
                                          W_l, b_l, W_r, out);

    int ib = (2 * NE + 255) / 256;
    eidx_kernel<<<ib, 256, 0, stream>>>(ei, out + (size_t)NN * DD);
}